// Round 1
// baseline (885.509 us; speedup 1.0000x reference)
//
#include <hip/hip_runtime.h>
#include <stdint.h>

// RetentionPolicy forward (training branch) for MI355X.
// One block (256 threads) per row. Row's 8192 logits live in registers
// (32 x uint32 orderable keys / thread). Selection = threshold filter with
// exact composite keys (value<<13 | (8191-idx)) -> matches jax.lax.top_k
// tie-breaking (lower index wins) exactly, then small bitonic sorts in LDS.

#define BSZ   16384
#define KDIM  8192
#define MAXC  100
#define TMIN  20
#define CAP   2048   // candidate buffer capacity (16 KB LDS)

__device__ __forceinline__ uint32_t okey(float x) {
  uint32_t b = __float_as_uint(x);
  return (b & 0x80000000u) ? ~b : (b | 0x80000000u);   // monotone float->uint
}

__global__ __launch_bounds__(256, 4)
void retention_kernel(const float* __restrict__ in,
                      int* __restrict__ out_bs,
                      int* __restrict__ out_cls,
                      int* __restrict__ out_mask) {
  const int tid  = threadIdx.x;
  const int row  = blockIdx.x;
  const int lane = tid & 63;
  const int wv   = tid >> 6;

  __shared__ unsigned long long buf[CAP];
  __shared__ int red[4];
  __shared__ int sidx[128];
  __shared__ unsigned nb;

  const float4* src = (const float4*)(in + (size_t)row * KDIM);

  // ---- single global pass: load row, keep orderable keys in registers ----
  uint32_t rkey[32];
  int cpos = 0;
  #pragma unroll
  for (int j = 0; j < 8; ++j) {
    float4 f = src[tid + 256 * j];
    rkey[4*j+0] = okey(f.x); cpos += (f.x >= 0.0f);
    rkey[4*j+1] = okey(f.y); cpos += (f.y >= 0.0f);
    rkey[4*j+2] = okey(f.z); cpos += (f.z >= 0.0f);
    rkey[4*j+3] = okey(f.w); cpos += (f.w >= 0.0f);
  }

  // ---- block reduce count of (logit >= 0)  ->  T = clamp(cnt,20,100) ----
  #pragma unroll
  for (int off = 32; off; off >>= 1) cpos += __shfl_down(cpos, off, 64);
  if (lane == 0) red[wv] = cpos;
  __syncthreads();
  const int T = min(max(red[0] + red[1] + red[2] + red[3], TMIN), MAXC);

  // composite for slot (j,m): idx = 4*tid + 1024*j + m
  auto count_gt = [&](unsigned long long t) -> int {
    int c = 0;
    #pragma unroll
    for (int j = 0; j < 8; ++j) {
      #pragma unroll
      for (int m = 0; m < 4; ++m) {
        int idx = 4 * tid + 1024 * j + m;
        unsigned long long comp =
            ((unsigned long long)rkey[4*j+m] << 13) | (unsigned long long)(8191 - idx);
        c += (comp > t) ? 1 : 0;
      }
    }
    #pragma unroll
    for (int off = 32; off; off >>= 1) c += __shfl_down(c, off, 64);
    __syncthreads();                 // protect red[] reuse
    if (lane == 0) red[wv] = c;
    __syncthreads();
    return red[0] + red[1] + red[2] + red[3];
  };

  // ---- threshold: fast path logit > -2.0, bisect fallback (exact) ----
  unsigned long long t = (unsigned long long)0x3FFFFFFFull << 13; // okey(-2.0f)<<13
  int c = count_gt(t);
  if (c < T || c > CAP) {
    unsigned long long lo, hi;               // invariant: cnt(lo)>CAP, cnt(hi)<T
    if (c < T) { lo = 0; hi = t; } else { lo = t; hi = 1ull << 45; }
    while (true) {
      unsigned long long mid = lo + ((hi - lo) >> 1);
      c = count_gt(mid);
      if (c >= T && c <= CAP) { t = mid; break; }
      if (c < T) hi = mid; else lo = mid;
    }
  }
  const int M = c;   // number of composites > t, T <= M <= CAP

  // ---- compact survivors into LDS (ballot-aggregated append) ----
  if (tid == 0) nb = 0;
  __syncthreads();
  #pragma unroll
  for (int j = 0; j < 8; ++j) {
    #pragma unroll
    for (int m = 0; m < 4; ++m) {
      int idx = 4 * tid + 1024 * j + m;
      unsigned long long comp =
          ((unsigned long long)rkey[4*j+m] << 13) | (unsigned long long)(8191 - idx);
      bool q = comp > t;
      unsigned long long mk = __ballot(q);
      int cnt = __popcll(mk);
      unsigned bw = 0;
      if (lane == 0 && cnt) bw = atomicAdd(&nb, (unsigned)cnt);
      bw = __shfl(bw, 0, 64);
      if (q) buf[bw + __popcll(mk & ((1ull << lane) - 1ull))] = comp;
    }
  }
  __syncthreads();

  // ---- bitonic sort buf[0..P) descending (pad with 0 = smallest) ----
  int P = 128;
  while (P < M) P <<= 1;                       // P <= CAP
  for (int i = M + tid; i < P; i += 256) buf[i] = 0ull;

  for (int k = 2; k <= P; k <<= 1) {
    for (int j = k >> 1; j > 0; j >>= 1) {
      __syncthreads();
      for (int i = tid; i < P; i += 256) {
        int ix = i ^ j;
        if (ix > i) {
          unsigned long long a = buf[i], b = buf[ix];
          bool dn = ((i & k) == 0);            // descending overall
          if (dn ? (a < b) : (a > b)) { buf[i] = b; buf[ix] = a; }
        }
      }
    }
  }
  __syncthreads();

  // ---- top-T indices, sort ascending (128-wide bitonic) ----
  if (tid < 128)
    sidx[tid] = (tid < T) ? (8191 - (int)(buf[tid] & 8191ull)) : 0x7fffffff;

  for (int k = 2; k <= 128; k <<= 1) {
    for (int j = k >> 1; j > 0; j >>= 1) {
      __syncthreads();
      if (tid < 128) {
        int i = tid, ix = i ^ j;
        if (ix > i) {
          int a = sidx[i], b = sidx[ix];
          if (((i & k) == 0) ? (a > b) : (a < b)) { sidx[i] = b; sidx[ix] = a; }
        }
      }
    }
  }
  __syncthreads();

  // ---- emit bs_idx / cls_idx / mask ----
  if (tid < MAXC) {
    bool v = tid < T;
    size_t o = (size_t)row * MAXC + tid;
    out_bs[o]   = v ? row : -1;
    out_cls[o]  = v ? sidx[tid] : -1;
    out_mask[o] = v ? 1 : 0;
  }
}

extern "C" void kernel_launch(void* const* d_in, const int* in_sizes, int n_in,
                              void* d_out, int out_size, void* d_ws, size_t ws_size,
                              hipStream_t stream) {
  const float* logits = (const float*)d_in[0];
  int* out = (int*)d_out;                      // int32 outputs, concatenated
  int* out_bs   = out;
  int* out_cls  = out + (size_t)BSZ * MAXC;
  int* out_mask = out + 2 * (size_t)BSZ * MAXC;
  retention_kernel<<<BSZ, 256, 0, stream>>>(logits, out_bs, out_cls, out_mask);
}

// Round 2
// 697.517 us; speedup vs baseline: 1.2695x; 1.2695x over previous
//
#include <hip/hip_runtime.h>
#include <stdint.h>

// RetentionPolicy forward (training) for MI355X — round 2.
// One block (256 thr) per row. Streaming pass: load row once (coalesced
// float4), count x>=0 (-> T), append survivors (x >= -2.0, ~187/row) into LDS
// as exact 45-bit composites (okey<<13 | (8191-idx)) during the load.
// Selection+sort: 256-wide bitonic in REGISTERS via __shfl_xor (33 in-wave
// stages, 3 LDS cross-wave stages) -> thread i holds i-th largest. Then
// 128-wide register bitonic ascending on the top-T class indices.
// Fallbacks (block-uniform, never taken on this data, correctness only):
//   256 < M <= 2048 -> LDS bitonic;  M < T or M > 2048 -> global bisect.

#define BSZ   16384
#define KDIM  8192
#define MAXC  100
#define TMIN  20
#define CAP   2048

__device__ __forceinline__ uint32_t okey(float x) {
  uint32_t b = __float_as_uint(x);
  return (b & 0x80000000u) ? ~b : (b | 0x80000000u);   // monotone float->uint
}

__global__ __launch_bounds__(256, 8)
void retention_kernel(const float* __restrict__ in,
                      int* __restrict__ out_bs,
                      int* __restrict__ out_cls,
                      int* __restrict__ out_mask) {
  const int tid  = threadIdx.x;
  const int row  = blockIdx.x;
  const int lane = tid & 63;
  const int wv   = tid >> 6;

  __shared__ unsigned long long buf[CAP];
  __shared__ int red[4];
  __shared__ unsigned nb;

  const float4* src = (const float4*)(in + (size_t)row * KDIM);

  if (tid == 0) nb = 0u;
  __syncthreads();

  // ---- single streaming pass: count positives, append survivors ----
  int cpos = 0;
  #pragma unroll
  for (int b = 0; b < 2; ++b) {
    float4 f[4];
    #pragma unroll
    for (int j = 0; j < 4; ++j) f[j] = src[tid + 256 * (4 * b + j)];
    #pragma unroll
    for (int j = 0; j < 4; ++j) {
      float v[4] = {f[j].x, f[j].y, f[j].z, f[j].w};
      #pragma unroll
      for (int m = 0; m < 4; ++m) {
        float x = v[m];
        cpos += (x >= 0.0f);
        if (x >= -2.0f) {                       // superset of comp > t0: exact
          int idx = 4 * tid + 1024 * (4 * b + j) + m;
          unsigned long long comp =
              ((unsigned long long)okey(x) << 13) | (unsigned long long)(8191 - idx);
          unsigned p = atomicAdd(&nb, 1u);
          if (p < CAP) buf[p] = comp;
        }
      }
    }
  }

  #pragma unroll
  for (int off = 32; off; off >>= 1) cpos += __shfl_down(cpos, off, 64);
  if (lane == 0) red[wv] = cpos;
  __syncthreads();                               // covers red, nb, buf
  const int T = min(max(red[0] + red[1] + red[2] + red[3], TMIN), MAXC);
  int M = (int)nb;

  // ---- Tier C fallback: global bisect to a count in [T, CAP] (exact) ----
  if (M < T || M > CAP) {
    auto count_gt_global = [&](unsigned long long t) -> int {
      int c = 0;
      for (int g = 0; g < 8; ++g) {
        float4 f = src[tid + 256 * g];
        float v[4] = {f.x, f.y, f.z, f.w};
        for (int m = 0; m < 4; ++m) {
          int idx = 4 * tid + 1024 * g + m;
          unsigned long long comp =
              ((unsigned long long)okey(v[m]) << 13) | (unsigned long long)(8191 - idx);
          c += (comp > t) ? 1 : 0;
        }
      }
      for (int off = 32; off; off >>= 1) c += __shfl_down(c, off, 64);
      __syncthreads();
      if (lane == 0) red[wv] = c;
      __syncthreads();
      return red[0] + red[1] + red[2] + red[3];
    };
    unsigned long long lo = 0, hi = 1ull << 45, t = 0;
    while (true) {                    // distinct composites => terminates
      unsigned long long mid = lo + ((hi - lo) >> 1);
      int c = count_gt_global(mid);
      if (c >= T && c <= CAP) { t = mid; M = c; break; }
      if (c < T) hi = mid; else lo = mid;
    }
    __syncthreads();
    if (tid == 0) nb = 0u;
    __syncthreads();
    for (int g = 0; g < 8; ++g) {
      float4 f = src[tid + 256 * g];
      float v[4] = {f.x, f.y, f.z, f.w};
      for (int m = 0; m < 4; ++m) {
        int idx = 4 * tid + 1024 * g + m;
        unsigned long long comp =
            ((unsigned long long)okey(v[m]) << 13) | (unsigned long long)(8191 - idx);
        if (comp > t) { unsigned p = atomicAdd(&nb, 1u); buf[p] = comp; }
      }
    }
    __syncthreads();
  }

  // ---- sort candidates descending; thread i ends holding i-th largest ----
  unsigned long long my;
  if (M <= 256) {
    // register bitonic across 256 threads (element-per-thread)
    my = (tid < M) ? buf[tid] : 0ull;            // pad 0 < any survivor comp
    #pragma unroll
    for (int k = 2; k <= 256; k <<= 1) {
      #pragma unroll
      for (int j = k >> 1; j; j >>= 1) {
        const bool dn = ((tid & k) == 0);        // overall descending at k=256
        const bool keep_max = (((tid & j) == 0) == dn);
        unsigned long long other;
        if (j < 64) {
          other = __shfl_xor(my, j, 64);
        } else {
          __syncthreads();
          buf[tid] = my;
          __syncthreads();
          other = buf[tid ^ j];
        }
        const bool gt = my > other;
        my = (gt == keep_max) ? my : other;
      }
    }
  } else {
    // LDS bitonic (rare fallback), P up to CAP
    int P = 256;
    while (P < M) P <<= 1;
    for (int i = M + tid; i < P; i += 256) buf[i] = 0ull;
    for (int k = 2; k <= P; k <<= 1) {
      for (int j = k >> 1; j; j >>= 1) {
        __syncthreads();
        for (int i = tid; i < P; i += 256) {
          int ix = i ^ j;
          if (ix > i) {
            unsigned long long a = buf[i], b2 = buf[ix];
            bool dnn = ((i & k) == 0);
            if (dnn ? (a < b2) : (a > b2)) { buf[i] = b2; buf[ix] = a; }
          }
        }
      }
    }
    __syncthreads();
    my = buf[tid];
  }

  // ---- top-T class indices, 128-wide register bitonic ascending ----
  int* ibuf = (int*)buf;
  int ibx = (tid < T) ? (8191 - (int)(my & 8191ull)) : 0x7FFFFFFF;
  #pragma unroll
  for (int k = 2; k <= 128; k <<= 1) {
    #pragma unroll
    for (int j = k >> 1; j; j >>= 1) {
      const bool dn = ((tid & k) != 0);          // overall ascending at k=128
      const bool keep_max = (((tid & j) == 0) == dn);
      if (j < 64) {
        int other = __shfl_xor(ibx, j, 64);
        if (tid < 128) {
          const bool gt = ibx > other;
          ibx = (gt == keep_max) ? ibx : other;
        }
      } else {
        __syncthreads();
        if (tid < 128) ibuf[tid] = ibx;
        __syncthreads();
        if (tid < 128) {
          int other = ibuf[tid ^ j];
          const bool gt = ibx > other;
          ibx = (gt == keep_max) ? ibx : other;
        }
      }
    }
  }

  // ---- emit ----
  if (tid < MAXC) {
    const bool v = tid < T;
    const size_t o = (size_t)row * MAXC + tid;
    out_bs[o]   = v ? row : -1;
    out_cls[o]  = v ? ibx : -1;
    out_mask[o] = v ? 1 : 0;
  }
}

extern "C" void kernel_launch(void* const* d_in, const int* in_sizes, int n_in,
                              void* d_out, int out_size, void* d_ws, size_t ws_size,
                              hipStream_t stream) {
  const float* logits = (const float*)d_in[0];
  int* out = (int*)d_out;
  int* out_bs   = out;
  int* out_cls  = out + (size_t)BSZ * MAXC;
  int* out_mask = out + 2 * (size_t)BSZ * MAXC;
  retention_kernel<<<BSZ, 256, 0, stream>>>(logits, out_bs, out_cls, out_mask);
}

// Round 3
// 690.693 us; speedup vs baseline: 1.2821x; 1.0099x over previous
//
#include <hip/hip_runtime.h>
#include <stdint.h>

// RetentionPolicy forward (training) — round 3.
// One block (256 thr) per row. Stream pass: coalesced float4 load, ballot-
// aggregated append of survivors (x >= -2.0, ~187/row) into LDS as
// (okey32<<32)|idx. ONE barrier. Then wave 0 alone, wave-synchronous:
//   - candidates -> registers (4/lane)
//   - T from count of positives (ballot popcount)
//   - T-th largest value via 32-step BALLOT BISECTION (VALU/SALU only — no
//     LDS pipe, no barriers); exact index tie-break via 13-step idx bisect
//   - selected indices compacted, 128-wide 2/lane shuffle bitonic ascending
//   - emit bs/cls/mask
// Fallbacks (stats-never, correctness only): M<20 or M>256 -> wave-local
// exact 45-bit composite bisect over the row re-read from global.

#define BSZ   16384
#define KDIM  8192
#define MAXC  100
#define TMIN  20
#define CAP   256

__device__ __forceinline__ uint32_t okey(float x) {
  uint32_t b = __float_as_uint(x);
  return (b & 0x80000000u) ? ~b : (b | 0x80000000u);   // monotone float->uint
}

__global__ __launch_bounds__(256, 8)
void retention_kernel(const float* __restrict__ in,
                      int* __restrict__ out_bs,
                      int* __restrict__ out_cls,
                      int* __restrict__ out_mask) {
  const int tid  = threadIdx.x;
  const int row  = blockIdx.x;
  const int lane = tid & 63;

  __shared__ unsigned long long buf[CAP];
  __shared__ int sidx[128];
  __shared__ unsigned nb;

  const float4* src = (const float4*)(in + (size_t)row * KDIM);

  if (tid == 0) nb = 0u;
  __syncthreads();

  // ---- streaming filter: append survivors, ballot-aggregated ----
  #pragma unroll
  for (int b = 0; b < 2; ++b) {
    float4 f[4];
    #pragma unroll
    for (int j = 0; j < 4; ++j) f[j] = src[tid + 256 * (4 * b + j)];
    #pragma unroll
    for (int j = 0; j < 4; ++j) {
      float v[4] = {f[j].x, f[j].y, f[j].z, f[j].w};
      #pragma unroll
      for (int m = 0; m < 4; ++m) {
        float x = v[m];
        bool q = (x >= -2.0f);
        unsigned long long mk = __ballot(q);
        if (mk) {
          unsigned bw = 0;
          if (lane == 0) bw = atomicAdd(&nb, (unsigned)__popcll(mk));
          bw = (unsigned)__shfl((int)bw, 0, 64);
          if (q) {
            unsigned p = bw + (unsigned)__popcll(mk & ((1ull << lane) - 1ull));
            if (p < CAP) {
              int idx = 4 * tid + 1024 * (4 * b + j) + m;
              buf[p] = ((unsigned long long)okey(x) << 32) | (unsigned)idx;
            }
          }
        }
      }
    }
  }
  __syncthreads();

  if (tid >= 64) return;            // tail: wave 0 only, wave-synchronous
  int M = (int)nb;
  int T = -1;                       // set by fallback if taken

  // ---- fallback: exact composite bisect over global (never taken) ----
  if (M < TMIN || M > CAP) {
    const float* rp = in + (size_t)row * KDIM;
    int cp = 0;
    for (int e = lane; e < KDIM; e += 64) cp += (rp[e] >= 0.0f);
    #pragma unroll
    for (int off = 32; off; off >>= 1) cp += __shfl_down(cp, off, 64);
    cp = __shfl(cp, 0, 64);
    T = min(max(cp, TMIN), MAXC);

    unsigned long long lo = 0, hi = 1ull << 45, t = 0;
    int c;
    while (true) {                  // distinct composites => terminates
      unsigned long long mid = lo + ((hi - lo) >> 1);
      c = 0;
      for (int e = lane; e < KDIM; e += 64) {
        unsigned long long comp =
            ((unsigned long long)okey(rp[e]) << 13) | (unsigned)(8191 - e);
        c += (comp > mid) ? 1 : 0;
      }
      #pragma unroll
      for (int off = 32; off; off >>= 1) c += __shfl_down(c, off, 64);
      c = __shfl(c, 0, 64);
      if (c >= T && c <= CAP) { t = mid; break; }
      if (c < T) hi = mid; else lo = mid;
    }
    unsigned base = 0;              // wave-local refill, no atomics
    for (int e = lane; e < KDIM; e += 64) {
      unsigned long long comp =
          ((unsigned long long)okey(rp[e]) << 13) | (unsigned)(8191 - e);
      bool q = comp > t;
      unsigned long long mk = __ballot(q);
      if (q) buf[base + (unsigned)__popcll(mk & ((1ull << lane) - 1ull))] =
                 ((unsigned long long)okey(rp[e]) << 32) | (unsigned)e;
      base += (unsigned)__popcll(mk);
    }
    M = c;
    __threadfence_block();
  }

  // ---- candidates -> registers (pad: val=0, ix=0x7FFF never selected) ----
  uint32_t val[4]; int ix[4];
  #pragma unroll
  for (int r = 0; r < 4; ++r) {
    int s = r * 64 + lane;
    unsigned long long c = (s < M) ? buf[s] : 0x0000000000007FFFull;
    val[r] = (uint32_t)(c >> 32);
    ix[r]  = (int)(c & 0xFFFFFFFFull);
  }

  if (T < 0) {                      // main path: positives from candidates
    int cp = 0;
    #pragma unroll
    for (int r = 0; r < 4; ++r)
      cp += (int)__popcll(__ballot((val[r] & 0x80000000u) != 0u));
    T = min(max(cp, TMIN), MAXC);
  }

  // ---- T-th largest value: 32-step ballot bisect (VALU/SALU only) ----
  uint32_t blo = 0, bhi = 0xFFFFFFFFu;
  while (blo < bhi) {
    uint32_t mid = blo + ((bhi - blo) >> 1);
    int c = 0;
    #pragma unroll
    for (int r = 0; r < 4; ++r) c += (int)__popcll(__ballot(val[r] > mid));
    if (c < T) bhi = mid; else blo = mid + 1;
  }
  const uint32_t vT = blo;          // smallest w with #(val>w) < T
  int c_gt = 0, c_eq = 0;
  #pragma unroll
  for (int r = 0; r < 4; ++r) {
    c_gt += (int)__popcll(__ballot(val[r] > vT));
    c_eq += (int)__popcll(__ballot(val[r] == vT));
  }
  const int need = T - c_gt;        // >= 1, <= c_eq
  int dcut = 0x3FFF;                // select ties with idx <= dcut (excl. pads)
  if (c_eq != need) {               // rare: float-equal tie straddles rank T
    int lo2 = 0, hi2 = 0x7FFF;
    while (lo2 < hi2) {
      int mid = (lo2 + hi2) >> 1;
      int g = 0;
      #pragma unroll
      for (int r = 0; r < 4; ++r)
        g += (int)__popcll(__ballot(val[r] == vT && ix[r] <= mid));
      if (g >= need) hi2 = mid; else lo2 = mid + 1;
    }
    dcut = lo2;                     // exactly `need` ties have idx <= dcut
  }

  // ---- compact exactly-T selected indices into LDS ----
  unsigned base = 0;
  #pragma unroll
  for (int r = 0; r < 4; ++r) {
    bool sel = (val[r] > vT) || (val[r] == vT && ix[r] <= dcut);
    unsigned long long mk = __ballot(sel);
    if (sel) sidx[base + (unsigned)__popcll(mk & ((1ull << lane) - 1ull))] = ix[r];
    base += (unsigned)__popcll(mk);
  }
  __threadfence_block();            // wave-synchronous LDS write->read

  // ---- ascending sort of 128 (2/lane), wave-synchronous shuffle bitonic ----
  int a0 = (lane < T)      ? sidx[lane]      : 0x7FFFFFFF;
  int a1 = (64 + lane < T) ? sidx[64 + lane] : 0x7FFFFFFF;
  #pragma unroll
  for (int k = 2; k <= 128; k <<= 1) {
    for (int j = k >> 1; j; j >>= 1) {
      if (j == 64) {                // only at k=128; both halves ascending
        int mn = min(a0, a1), mx = max(a0, a1);
        a0 = mn; a1 = mx;
      } else {
        int o0 = __shfl_xor(a0, j, 64);
        int o1 = __shfl_xor(a1, j, 64);
        const bool lower = (lane & j) == 0;
        const bool asc0 = ((lane & k) == 0);
        const bool asc1 = (((64 + lane) & k) == 0);
        a0 = (lower != asc0) ? max(a0, o0) : min(a0, o0);
        a1 = (lower != asc1) ? max(a1, o1) : min(a1, o1);
      }
    }
  }

  // ---- emit ----
  const size_t o = (size_t)row * MAXC;
  if (lane < MAXC) {
    const bool vv = lane < T;
    out_bs[o + lane]   = vv ? row : -1;
    out_cls[o + lane]  = vv ? a0 : -1;
    out_mask[o + lane] = vv ? 1 : 0;
  }
  const int p = 64 + lane;
  if (p < MAXC) {
    const bool vv = p < T;
    out_bs[o + p]   = vv ? row : -1;
    out_cls[o + p]  = vv ? a1 : -1;
    out_mask[o + p] = vv ? 1 : 0;
  }
}

extern "C" void kernel_launch(void* const* d_in, const int* in_sizes, int n_in,
                              void* d_out, int out_size, void* d_ws, size_t ws_size,
                              hipStream_t stream) {
  const float* logits = (const float*)d_in[0];
  int* out = (int*)d_out;
  int* out_bs   = out;
  int* out_cls  = out + (size_t)BSZ * MAXC;
  int* out_mask = out + 2 * (size_t)BSZ * MAXC;
  retention_kernel<<<BSZ, 256, 0, stream>>>(logits, out_bs, out_cls, out_mask);
}